// Round 8
// baseline (23302.762 us; speedup 1.0000x reference)
//
#include <hip/hip_runtime.h>
#include <hip/hip_fp16.h>

#define BB 128
#define II 64
#define SS 2048
#define HH 128
#define GG 512   // 4*H
#define OO 64
#define TT 32    // x time-tile width (fallback kernel)
#define TCH 128  // precompute t-chunk
#define XPBYTES ((size_t)BB * SS * GG * 2)

typedef _Float16 f16x2 __attribute__((ext_vector_type(2)));
union F4H { float4 f4; f16x2 h[4]; };

__device__ __forceinline__ f16x2 pack2(float a, float b) {
    f16x2 r; r.x = (_Float16)a; r.y = (_Float16)b; return r;
}

__device__ __forceinline__ float dot2(f16x2 w, f16x2 v, float c) {
#if __has_builtin(__builtin_amdgcn_fdot2)
    return __builtin_amdgcn_fdot2(w, v, c, false);
#else
    return fmaf((float)w.x, (float)v.x, fmaf((float)w.y, (float)v.y, c));
#endif
}

__device__ __forceinline__ float sigm(float v) {
    return __builtin_amdgcn_rcpf(1.0f + __expf(-v));
}
// original tanh (fallback kernel keeps R1 bit-exact behavior)
__device__ __forceinline__ float tanh_f(float v) {
    float a = fabsf(v);
    float e = __expf(-2.0f * a);
    float r = (1.0f - e) * __builtin_amdgcn_rcpf(1.0f + e);
    return v < 0.0f ? -r : r;
}
// branch-free tanh = 2*sigm(2v)-1 (safe at +/-inf)
__device__ __forceinline__ float tanh_c(float v) {
    return fmaf(2.0f, __builtin_amdgcn_rcpf(1.0f + __expf(-2.0f * v)), -1.0f);
}

// quad-scope shuffle via DPP quad_perm (VALU pipe, ~4cyc; replaces the
// ds_swizzle that __shfl_xor lowers to, ~30cyc on the LDS pipe).
// CTRL = perm[0] | perm[1]<<2 | perm[2]<<4 | perm[3]<<6
template <int CTRL>
__device__ __forceinline__ float qdpp(float x) {
    return __int_as_float(__builtin_amdgcn_update_dpp(
        0, __float_as_int(x), CTRL, 0xF, 0xF, true));
}
#define QP_XOR3 0x1B   // [3,2,1,0]
#define QP_BC0  0x00   // [0,0,0,0]
#define QP_BC1  0x55   // [1,1,1,1]
#define QP_BC2  0xAA   // [2,2,2,2]

// ============================================================================
// XP precompute: XP[b][t][j] = sum_i x[b,i,t] * Wx_out[i,j], stored f16.
// ============================================================================
__global__ void __launch_bounds__(512)
xp_gemm(const float* __restrict__ x, const float* __restrict__ Wx_out,
        _Float16* __restrict__ xp)
{
    const int tc = blockIdx.x;          // 0..15
    const int b  = blockIdx.y;          // 0..127
    const int j  = threadIdx.x;         // gate column 0..511
    const int t0 = tc * TCH;

    __shared__ __align__(16) f16x2 x2s[TCH][36];

    f16x2 w2[32];
#pragma unroll
    for (int c = 0; c < 32; ++c)
        w2[c] = pack2(Wx_out[(2 * c) * GG + j], Wx_out[(2 * c + 1) * GG + j]);

    const float* xrow = x + (size_t)b * II * SS;
    const int r = j >> 3;
#pragma unroll
    for (int rep = 0; rep < 4; ++rep) {
        const int u = (j & 7) + 8 * rep;
        const float4 v = *(const float4*)(xrow + (size_t)r * SS + t0 + 4 * u);
        const int c = r >> 1, half = r & 1;
        ((_Float16*)&x2s[4 * u + 0][c])[half] = (_Float16)v.x;
        ((_Float16*)&x2s[4 * u + 1][c])[half] = (_Float16)v.y;
        ((_Float16*)&x2s[4 * u + 2][c])[half] = (_Float16)v.z;
        ((_Float16*)&x2s[4 * u + 3][c])[half] = (_Float16)v.w;
    }
    __syncthreads();

    _Float16* xpo = xp + ((size_t)b * SS + t0) * GG + j;
#pragma unroll 4
    for (int tt = 0; tt < TCH; ++tt) {
        const float4* xr4 = (const float4*)&x2s[tt][0];
        float a0 = 0.f, a1 = 0.f;
#pragma unroll
        for (int q = 0; q < 8; ++q) {
            F4H u; u.f4 = xr4[q];
            a0 = dot2(w2[4 * q + 0], u.h[0], a0);
            a1 = dot2(w2[4 * q + 1], u.h[1], a1);
            a0 = dot2(w2[4 * q + 2], u.h[2], a0);
            a1 = dot2(w2[4 * q + 3], u.h[3], a1);
        }
        xpo[(size_t)tt * GG] = (_Float16)(a0 + a1);
    }
}

// ============================================================================
// Scan, quad-gate layout + DPP update + dbuf-h + in-window projection.
//   thread j: gate g=j&3 of h-column m=j>>2 (col = g*128+m).
//   c/cn carried REDUNDANTLY in all 4 quad lanes -> state update is local
//   math after 3 independent DPP broadcasts (no serial shuffle chain).
//   hb double-buffered: C(t) writes hb[t&1]; A(t)/E(t-1) read hb[t&1^1],
//   so the projection E(t-1) runs INSIDE the C(t) window as chain filler.
//   8 accumulators per dot phase (chain 16 deep -> 8).  2 barriers/step.
// ============================================================================
__global__ void __launch_bounds__(512)
nlstm_scan_xp(
    const _Float16* __restrict__ xp,
    const float* __restrict__ Wh_out, const float* __restrict__ b_out,
    const float* __restrict__ Wx_in, const float* __restrict__ Wh_in,
    const float* __restrict__ b_in,
    const float* __restrict__ W_lin, const float* __restrict__ b_lin,
    float* __restrict__ out)
{
    const int b = blockIdx.x;
    const int j = threadIdx.x;
    const int g = j & 3;          // gate lane within quad: 0=i 1=f 2=o 3=g
    const int m = j >> 2;         // h-column 0..127
    const int col = g * 128 + m;  // gate column in canonical layout

    __shared__ __align__(16) float4 wlf[16 * 66];      // W_lin fp16, 16.5 KB
    __shared__ __align__(16) _Float16 hb[2][HH];       // h fp16, double-buffered
    __shared__ __align__(16) _Float16 xib[HH];         // x_in fp16
    __shared__ __align__(16) _Float16 hib[HH];         // h_in fp16

    // register-resident fp16 weights (column col) : 192 regs (AGPR-backed)
    f16x2 who[HH / 2], wxi[HH / 2], whi[HH / 2];
#pragma unroll
    for (int q = 0; q < HH / 2; ++q)
        who[q] = pack2(Wh_out[(2 * q) * GG + col], Wh_out[(2 * q + 1) * GG + col]);
#pragma unroll
    for (int q = 0; q < HH / 2; ++q)
        wxi[q] = pack2(Wx_in[(2 * q) * GG + col], Wx_in[(2 * q + 1) * GG + col]);
#pragma unroll
    for (int q = 0; q < HH / 2; ++q)
        whi[q] = pack2(Wh_in[(2 * q) * GG + col], Wh_in[(2 * q + 1) * GG + col]);

    const float bo = b_out[col];
    const float bi = b_in[col];
    // branch-free activation: g<3 -> sigm(x); g==3 -> tanh(x)=2*sigm(2x)-1
    const float kk = (g == 3) ? 2.0f : 1.0f;
    const float aa = (g == 3) ? 2.0f : 1.0f;
    const float cc = (g == 3) ? -1.0f : 0.0f;

    const int   pn = j >> 3;
    const int   ps = j & 7;
    const float bl = b_lin[pn];

    // W_lin -> LDS fp16 (1024 chunks, 2 per thread)
#pragma unroll
    for (int r = 0; r < 2; ++r) {
        const int mm = r * 512 + j;
        const int c = mm >> 6, n = mm & 63;
        F4H u;
#pragma unroll
        for (int q = 0; q < 4; ++q)
            u.h[q] = pack2(W_lin[n * HH + 8 * c + 2 * q],
                           W_lin[n * HH + 8 * c + 2 * q + 1]);
        wlf[c * 66 + n] = u.f4;
    }

    if (j < HH) hb[1][j] = (_Float16)0.f;   // A(0)/E(-1) buffer
    float c_reg = 0.f, cn_reg = 0.f;        // redundant in all 4 quad lanes
    float o_all = 0.f;                      // outer o, broadcast each step
    __syncthreads();

    const _Float16* xpr = xp + (size_t)b * SS * GG + col;
    float* orow = out + (size_t)b * SS * OO;
    const float4* xi4 = (const float4*)xib;  // 16 chunks
    const float4* hi4 = (const float4*)hib;  // 16 chunks

    _Float16 xpc = xpr[0];

#pragma unroll 1
    for (int t = 0; t < SS; ++t) {
        const int cur = t & 1, prv = cur ^ 1;
        const float4* hbP = (const float4*)hb[prv];   // h(t-1), 16 chunks

        // ---- phase A: outer gate for col = XP + h@Wh_out + b (8 accs) ----
        float av[8];
        av[0] = bo + (float)xpc;
#pragma unroll
        for (int q = 1; q < 8; ++q) av[q] = 0.f;
#pragma unroll
        for (int c = 0; c < 16; ++c) {
            F4H hu; hu.f4 = hbP[c];
            av[c & 7] = dot2(who[4 * c + 0], hu.h[0], av[c & 7]);
            av[c & 7] = dot2(who[4 * c + 1], hu.h[1], av[c & 7]);
            av[c & 7] = dot2(who[4 * c + 2], hu.h[2], av[c & 7]);
            av[c & 7] = dot2(who[4 * c + 3], hu.h[3], av[c & 7]);
        }
        // prefetch next step's XP (independent; lands during phase C)
        const _Float16 xpn = xpr[(size_t)((t + 1) & (SS - 1)) * GG];
        const float accA = ((av[0] + av[1]) + (av[2] + av[3]))
                         + ((av[4] + av[5]) + (av[6] + av[7]));
        const float v = fmaf(aa, sigm(kk * accA), cc);   // i/f/o/g by lane
        // quad tail (DPP): x_in = i*g at lane0, h_in = f*c_prev at lane1
        const float vg3 = qdpp<QP_XOR3>(v);   // lane0 <- g-value
        o_all = qdpp<QP_BC2>(v);              // everyone keeps outer o
        if (g == 0)      xib[m] = (_Float16)(v * vg3);
        else if (g == 1) hib[m] = (_Float16)(v * c_reg);
        __syncthreads();   // S1

        // ---- phase C: inner gate for col (8 accs) ----
        float cv[8];
        cv[0] = bi;
#pragma unroll
        for (int q = 1; q < 8; ++q) cv[q] = 0.f;
#pragma unroll
        for (int c = 0; c < 16; ++c) {
            F4H xu; xu.f4 = xi4[c];
            cv[c & 7] = dot2(wxi[4 * c + 0], xu.h[0], cv[c & 7]);
            cv[c & 7] = dot2(wxi[4 * c + 1], xu.h[1], cv[c & 7]);
            cv[c & 7] = dot2(wxi[4 * c + 2], xu.h[2], cv[c & 7]);
            cv[c & 7] = dot2(wxi[4 * c + 3], xu.h[3], cv[c & 7]);
        }
#pragma unroll
        for (int c = 0; c < 16; ++c) {
            F4H hu; hu.f4 = hi4[c];
            cv[c & 7] = dot2(whi[4 * c + 0], hu.h[0], cv[c & 7]);
            cv[c & 7] = dot2(whi[4 * c + 1], hu.h[1], cv[c & 7]);
            cv[c & 7] = dot2(whi[4 * c + 2], hu.h[2], cv[c & 7]);
            cv[c & 7] = dot2(whi[4 * c + 3], hu.h[3], cv[c & 7]);
        }

        // ---- projection E(t-1): independent filler for C's chain stalls ----
        // (reads hb[prv] = h(t-1); C writes hb[cur] -> no race, no barrier)
        if (t > 0) {
            float p = 0.f;
#pragma unroll
            for (int q = 0; q < 2; ++q) {
                const int c = 2 * ps + q;
                F4H hu; hu.f4 = hbP[c];
                F4H wu; wu.f4 = wlf[c * 66 + pn];
                p = dot2(wu.h[0], hu.h[0], p);
                p = dot2(wu.h[1], hu.h[1], p);
                p = dot2(wu.h[2], hu.h[2], p);
                p = dot2(wu.h[3], hu.h[3], p);
            }
            p += __shfl_down(p, 4, 8);
            p += __shfl_down(p, 2, 8);
            p += __shfl_down(p, 1, 8);
            if (ps == 0) orow[(size_t)(t - 1) * OO + pn] = p + bl;
        }

        const float accC = ((cv[0] + cv[1]) + (cv[2] + cv[3]))
                         + ((cv[4] + cv[5]) + (cv[6] + cv[7]));
        const float u = fmaf(aa, sigm(kk * accC), cc);    // ii/fi/oi/gi by lane
        // quad tail (DPP, redundant update in all lanes):
        const float ug3 = qdpp<QP_XOR3>(u);
        const float p0  = u * ug3;                 // ii*gi valid at lanes 0,3
        const float P   = qdpp<QP_BC0>(p0);        // ii*gi everywhere
        const float F   = qdpp<QP_BC1>(u);         // fi everywhere
        const float O   = qdpp<QP_BC2>(u);         // oi everywhere
        const float cn_new = fmaf(F, cn_reg, P);
        cn_reg = cn_new;
        const float c_new = O * tanh_c(cn_new);
        c_reg = c_new;
        const float h_new = o_all * tanh_c(c_new);
        if (g == 2) hb[cur][m] = (_Float16)h_new;
        xpc = xpn;
        __syncthreads();   // S2
    }

    // ---- epilogue: projection for t = SS-1 ----
    {
        const float4* hbL = (const float4*)hb[(SS - 1) & 1];
        float p = 0.f;
#pragma unroll
        for (int q = 0; q < 2; ++q) {
            const int c = 2 * ps + q;
            F4H hu; hu.f4 = hbL[c];
            F4H wu; wu.f4 = wlf[c * 66 + pn];
            p = dot2(wu.h[0], hu.h[0], p);
            p = dot2(wu.h[1], hu.h[1], p);
            p = dot2(wu.h[2], hu.h[2], p);
            p = dot2(wu.h[3], hu.h[3], p);
        }
        p += __shfl_down(p, 4, 8);
        p += __shfl_down(p, 2, 8);
        p += __shfl_down(p, 1, 8);
        if (ps == 0) orow[(size_t)(SS - 1) * OO + pn] = p + bl;
    }
}

// ============================================================================
// FALLBACK: exact R1 kernel (measured 4364 us) for when ws is too small.
// ============================================================================
__global__ void
__attribute__((amdgpu_flat_work_group_size(512, 512)))
__attribute__((amdgpu_waves_per_eu(2, 2)))
nlstm_scan(
    const float* __restrict__ x,
    const float* __restrict__ Wx_out, const float* __restrict__ Wh_out,
    const float* __restrict__ b_out,
    const float* __restrict__ Wx_in, const float* __restrict__ Wh_in,
    const float* __restrict__ b_in,
    const float* __restrict__ W_lin, const float* __restrict__ b_lin,
    float* __restrict__ out)
{
    const int b = blockIdx.x;
    const int j = threadIdx.x;

    __shared__ __align__(16) float4 wxf[8 * 512];
    __shared__ __align__(16) float4 wlf[16 * 66];
    __shared__ float xt[2][II][TT + 1];
    __shared__ __align__(16) f16x2 xb[2][II / 2];
    __shared__ __align__(16) f16x2 hb[HH / 2];
    __shared__ __align__(16) f16x2 xib[HH / 2];
    __shared__ __align__(16) f16x2 hib[HH / 2];
    __shared__ float cb[HH];
    __shared__ float cnb[HH];
    __shared__ float actO[GG];
    __shared__ float actI[GG];

    f16x2 who[HH / 2], wxi[HH / 2], whi[HH / 2];
#pragma unroll
    for (int m = 0; m < HH / 2; ++m)
        who[m] = pack2(Wh_out[(2 * m) * GG + j], Wh_out[(2 * m + 1) * GG + j]);
#pragma unroll
    for (int m = 0; m < HH / 2; ++m)
        wxi[m] = pack2(Wx_in[(2 * m) * GG + j], Wx_in[(2 * m + 1) * GG + j]);
#pragma unroll
    for (int m = 0; m < HH / 2; ++m)
        whi[m] = pack2(Wh_in[(2 * m) * GG + j], Wh_in[(2 * m + 1) * GG + j]);

    const float bo = b_out[j];
    const float bi = b_in[j];
    const int   pn = j >> 3;
    const int   ps = j & 7;
    const float bl = b_lin[pn];

#pragma unroll
    for (int c = 0; c < 8; ++c) {
        F4H u;
#pragma unroll
        for (int q = 0; q < 4; ++q)
            u.h[q] = pack2(Wx_out[(8 * c + 2 * q) * GG + j],
                           Wx_out[(8 * c + 2 * q + 1) * GG + j]);
        wxf[c * 512 + j] = u.f4;
    }
#pragma unroll
    for (int r = 0; r < 2; ++r) {
        const int m = r * 512 + j;
        const int c = m >> 6, n = m & 63;
        F4H u;
#pragma unroll
        for (int q = 0; q < 4; ++q)
            u.h[q] = pack2(W_lin[n * HH + 8 * c + 2 * q],
                           W_lin[n * HH + 8 * c + 2 * q + 1]);
        wlf[c * 66 + n] = u.f4;
    }

    const float* xrow = x + (size_t)b * II * SS;
    float* orow = out + (size_t)b * SS * OO;

    {
        const int row = j >> 3, tc = j & 7;
        const float4 v = *(const float4*)(xrow + (size_t)row * SS + 4 * tc);
        float* dst = &xt[0][row][4 * tc];
        dst[0] = v.x; dst[1] = v.y; dst[2] = v.z; dst[3] = v.w;
    }
    if (j < HH / 2) hb[j] = pack2(0.f, 0.f);
    if (j < HH) { cb[j] = 0.f; cnb[j] = 0.f; }
    if (j >= 256 && j < 256 + 32) {
        const int m = j - 256;
        xb[0][m] = pack2(xrow[(2 * m) * SS], xrow[(2 * m + 1) * SS]);
    }
    __syncthreads();

    const float4* hb4 = (const float4*)hb;
    const float4* xi4 = (const float4*)xib;
    const float4* hi4 = (const float4*)hib;

#pragma unroll 1
    for (int t = 0; t < SS; ++t) {
        const float4* xcur = (const float4*)xb[t & 1];
        float a0 = bo, a1 = 0.f, a2 = 0.f, a3 = 0.f;
#pragma unroll
        for (int c = 0; c < 8; ++c) {
            F4H xu; xu.f4 = xcur[c];
            F4H wu; wu.f4 = wxf[c * 512 + j];
            a0 = dot2(wu.h[0], xu.h[0], a0);
            a1 = dot2(wu.h[1], xu.h[1], a1);
            a2 = dot2(wu.h[2], xu.h[2], a2);
            a3 = dot2(wu.h[3], xu.h[3], a3);
        }
#pragma unroll
        for (int c = 0; c < 16; ++c) {
            F4H hu; hu.f4 = hb4[c];
            a0 = dot2(who[4 * c + 0], hu.h[0], a0);
            a1 = dot2(who[4 * c + 1], hu.h[1], a1);
            a2 = dot2(who[4 * c + 2], hu.h[2], a2);
            a3 = dot2(who[4 * c + 3], hu.h[3], a3);
        }
        {
            const float acc = (a0 + a1) + (a2 + a3);
            actO[j] = (j < 384) ? sigm(acc) : tanh_f(acc);
        }
        __syncthreads();

        if (j < II) {
            xib[j] = pack2(actO[2 * j] * actO[384 + 2 * j],
                           actO[2 * j + 1] * actO[384 + 2 * j + 1]);
        } else if (j < II + HH / 2) {
            const int m = j - II;
            hib[m] = pack2(actO[HH + 2 * m] * cb[2 * m],
                           actO[HH + 2 * m + 1] * cb[2 * m + 1]);
        }
        __syncthreads();

        float c0 = bi, c1 = 0.f, c2 = 0.f, c3 = 0.f;
#pragma unroll
        for (int c = 0; c < 16; ++c) {
            F4H xu; xu.f4 = xi4[c];
            c0 = dot2(wxi[4 * c + 0], xu.h[0], c0);
            c1 = dot2(wxi[4 * c + 1], xu.h[1], c1);
            c2 = dot2(wxi[4 * c + 2], xu.h[2], c2);
            c3 = dot2(wxi[4 * c + 3], xu.h[3], c3);
        }
#pragma unroll
        for (int c = 0; c < 16; ++c) {
            F4H hu; hu.f4 = hi4[c];
            c0 = dot2(whi[4 * c + 0], hu.h[0], c0);
            c1 = dot2(whi[4 * c + 1], hu.h[1], c1);
            c2 = dot2(whi[4 * c + 2], hu.h[2], c2);
            c3 = dot2(whi[4 * c + 3], hu.h[3], c3);
        }
        {
            const float acc2 = (c0 + c1) + (c2 + c3);
            actI[j] = (j < 384) ? sigm(acc2) : tanh_f(acc2);
        }
        __syncthreads();

        const bool doTile = ((t & 31) == 30) && (t + 2 < SS);
        float4 xld; int Tn = 0;
        if (doTile) {
            Tn = (t + 2) >> 5;
            const int row = j >> 3, tc = j & 7;
            xld = *(const float4*)(xrow + (size_t)row * SS + TT * Tn + 4 * tc);
        }
        if (j < HH) {
            const float cn_new = actI[HH + j] * cnb[j] + actI[j] * actI[384 + j];
            const float c_new  = actI[2 * HH + j] * tanh_f(cn_new);
            const float h_new  = actO[2 * HH + j] * tanh_f(c_new);
            cnb[j] = cn_new;
            cb[j]  = c_new;
            ((_Float16*)hb)[j] = (_Float16)h_new;
        } else if (j < HH + 32) {
            const int m = j - HH;
            const int tn = t + 1;
            const int tbn = (tn >> 5) & 1, ttn = tn & 31;
            xb[tn & 1][m] = pack2(xt[tbn][2 * m][ttn],
                                  xt[tbn][2 * m + 1][ttn]);
        }
        if (doTile) {
            const int row = j >> 3, tc = j & 7;
            float* dst = &xt[Tn & 1][row][4 * tc];
            dst[0] = xld.x; dst[1] = xld.y; dst[2] = xld.z; dst[3] = xld.w;
        }
        __syncthreads();

        float p = 0.f;
#pragma unroll
        for (int q = 0; q < 2; ++q) {
            const int c = 2 * ps + q;
            F4H hu; hu.f4 = hb4[c];
            F4H wu; wu.f4 = wlf[c * 66 + pn];
            p = dot2(wu.h[0], hu.h[0], p);
            p = dot2(wu.h[1], hu.h[1], p);
            p = dot2(wu.h[2], hu.h[2], p);
            p = dot2(wu.h[3], hu.h[3], p);
        }
        p += __shfl_down(p, 4, 8);
        p += __shfl_down(p, 2, 8);
        p += __shfl_down(p, 1, 8);
        if (ps == 0) orow[t * OO + pn] = p + bl;
    }
}

extern "C" void kernel_launch(void* const* d_in, const int* in_sizes, int n_in,
                              void* d_out, int out_size, void* d_ws, size_t ws_size,
                              hipStream_t stream) {
    (void)in_sizes; (void)n_in; (void)out_size;
    const float* x      = (const float*)d_in[0];
    const float* Wx_out = (const float*)d_in[1];
    const float* Wh_out = (const float*)d_in[2];
    const float* b_out  = (const float*)d_in[3];
    const float* Wx_in  = (const float*)d_in[4];
    const float* Wh_in  = (const float*)d_in[5];
    const float* b_in   = (const float*)d_in[6];
    const float* W_lin  = (const float*)d_in[7];
    const float* b_lin  = (const float*)d_in[8];
    float* out = (float*)d_out;

    if (d_ws != nullptr && ws_size >= XPBYTES) {
        _Float16* xpw = (_Float16*)d_ws;
        xp_gemm<<<dim3(16, BB), dim3(512), 0, stream>>>(x, Wx_out, xpw);
        nlstm_scan_xp<<<dim3(BB), dim3(512), 0, stream>>>(
            xpw, Wh_out, b_out, Wx_in, Wh_in, b_in, W_lin, b_lin, out);
    } else {
        nlstm_scan<<<dim3(BB), dim3(512), 0, stream>>>(
            x, Wx_out, Wh_out, b_out, Wx_in, Wh_in, b_in, W_lin, b_lin, out);
    }
}

// Round 9
// 3520.942 us; speedup vs baseline: 6.6183x; 6.6183x over previous
//
#include <hip/hip_runtime.h>
#include <hip/hip_fp16.h>

#define BB 128
#define II 64
#define SS 2048
#define HH 128
#define GG 512   // 4*H
#define OO 64
#define TT 32    // x time-tile width (fallback kernel)
#define TCH 128  // precompute t-chunk
#define XPBYTES ((size_t)BB * SS * GG * 2)

typedef _Float16 f16x2 __attribute__((ext_vector_type(2)));
union F4H { float4 f4; f16x2 h[4]; };

__device__ __forceinline__ f16x2 pack2(float a, float b) {
    f16x2 r; r.x = (_Float16)a; r.y = (_Float16)b; return r;
}

__device__ __forceinline__ float dot2(f16x2 w, f16x2 v, float c) {
#if __has_builtin(__builtin_amdgcn_fdot2)
    return __builtin_amdgcn_fdot2(w, v, c, false);
#else
    return fmaf((float)w.x, (float)v.x, fmaf((float)w.y, (float)v.y, c));
#endif
}

__device__ __forceinline__ float sigm(float v) {
    return __builtin_amdgcn_rcpf(1.0f + __expf(-v));
}
// original tanh (fallback kernel keeps R1 bit-exact behavior)
__device__ __forceinline__ float tanh_f(float v) {
    float a = fabsf(v);
    float e = __expf(-2.0f * a);
    float r = (1.0f - e) * __builtin_amdgcn_rcpf(1.0f + e);
    return v < 0.0f ? -r : r;
}
// branch-free tanh = 2*sigm(2v)-1 (safe at +/-inf)
__device__ __forceinline__ float tanh_c(float v) {
    return fmaf(2.0f, __builtin_amdgcn_rcpf(1.0f + __expf(-2.0f * v)), -1.0f);
}

// quad-scope shuffle via DPP quad_perm (VALU pipe ~4cyc; replaces the
// ds_swizzle that __shfl_xor lowers to, ~30cyc on the LDS pipe).
// CTRL = perm[0] | perm[1]<<2 | perm[2]<<4 | perm[3]<<6
template <int CTRL>
__device__ __forceinline__ float qdpp(float x) {
    return __int_as_float(__builtin_amdgcn_update_dpp(
        0, __float_as_int(x), CTRL, 0xF, 0xF, true));
}
#define QP_XOR3 0x1B   // [3,2,1,0]
#define QP_BC0  0x00   // [0,0,0,0]
#define QP_BC1  0x55   // [1,1,1,1]
#define QP_BC2  0xAA   // [2,2,2,2]

// ============================================================================
// XP precompute: XP[b][t][j] = sum_i x[b,i,t] * Wx_out[i,j], stored f16.
// ============================================================================
__global__ void __launch_bounds__(512)
xp_gemm(const float* __restrict__ x, const float* __restrict__ Wx_out,
        _Float16* __restrict__ xp)
{
    const int tc = blockIdx.x;          // 0..15
    const int b  = blockIdx.y;          // 0..127
    const int j  = threadIdx.x;         // gate column 0..511
    const int t0 = tc * TCH;

    __shared__ __align__(16) f16x2 x2s[TCH][36];

    f16x2 w2[32];
#pragma unroll
    for (int c = 0; c < 32; ++c)
        w2[c] = pack2(Wx_out[(2 * c) * GG + j], Wx_out[(2 * c + 1) * GG + j]);

    const float* xrow = x + (size_t)b * II * SS;
    const int r = j >> 3;
#pragma unroll
    for (int rep = 0; rep < 4; ++rep) {
        const int u = (j & 7) + 8 * rep;
        const float4 v = *(const float4*)(xrow + (size_t)r * SS + t0 + 4 * u);
        const int c = r >> 1, half = r & 1;
        ((_Float16*)&x2s[4 * u + 0][c])[half] = (_Float16)v.x;
        ((_Float16*)&x2s[4 * u + 1][c])[half] = (_Float16)v.y;
        ((_Float16*)&x2s[4 * u + 2][c])[half] = (_Float16)v.z;
        ((_Float16*)&x2s[4 * u + 3][c])[half] = (_Float16)v.w;
    }
    __syncthreads();

    _Float16* xpo = xp + ((size_t)b * SS + t0) * GG + j;
#pragma unroll 4
    for (int tt = 0; tt < TCH; ++tt) {
        const float4* xr4 = (const float4*)&x2s[tt][0];
        float a0 = 0.f, a1 = 0.f;
#pragma unroll
        for (int q = 0; q < 8; ++q) {
            F4H u; u.f4 = xr4[q];
            a0 = dot2(w2[4 * q + 0], u.h[0], a0);
            a1 = dot2(w2[4 * q + 1], u.h[1], a1);
            a0 = dot2(w2[4 * q + 2], u.h[2], a0);
            a1 = dot2(w2[4 * q + 3], u.h[3], a1);
        }
        xpo[(size_t)tt * GG] = (_Float16)(a0 + a1);
    }
}

// ============================================================================
// Scan, quad-gate layout (R7 structure, measured 3708us) with the two
// REGISTER-NEUTRAL upgrades from R8 (whose 8-acc + E-relocation caused
// scratch spill -> 890MB FETCH -> 6x regression; both reverted here):
//   - quad shuffles via DPP quad_perm (VALU ~4cyc vs ds_swizzle ~30cyc)
//   - c/cn redundant in all 4 quad lanes -> update broadcasts (P,F,O) all
//     depend only on u and issue back-to-back (no serial shuffle chain)
// Everything else identical to R7: 4 accumulators, single hb buffer,
// projection E after S2, 2 barriers/step.
// ============================================================================
__global__ void __launch_bounds__(512)
nlstm_scan_xp(
    const _Float16* __restrict__ xp,
    const float* __restrict__ Wh_out, const float* __restrict__ b_out,
    const float* __restrict__ Wx_in, const float* __restrict__ Wh_in,
    const float* __restrict__ b_in,
    const float* __restrict__ W_lin, const float* __restrict__ b_lin,
    float* __restrict__ out)
{
    const int b = blockIdx.x;
    const int j = threadIdx.x;
    const int g = j & 3;          // gate lane within quad: 0=i 1=f 2=o 3=g
    const int m = j >> 2;         // h-column 0..127
    const int col = g * 128 + m;  // gate column in canonical layout

    __shared__ __align__(16) float4 wlf[16 * 66];      // W_lin fp16, 16.5 KB
    __shared__ __align__(16) _Float16 hb[HH];          // h fp16
    __shared__ __align__(16) _Float16 xib[HH];         // x_in fp16
    __shared__ __align__(16) _Float16 hib[HH];         // h_in fp16

    // register-resident fp16 weights (column col) : 192 regs (AGPR-backed)
    f16x2 who[HH / 2], wxi[HH / 2], whi[HH / 2];
#pragma unroll
    for (int q = 0; q < HH / 2; ++q)
        who[q] = pack2(Wh_out[(2 * q) * GG + col], Wh_out[(2 * q + 1) * GG + col]);
#pragma unroll
    for (int q = 0; q < HH / 2; ++q)
        wxi[q] = pack2(Wx_in[(2 * q) * GG + col], Wx_in[(2 * q + 1) * GG + col]);
#pragma unroll
    for (int q = 0; q < HH / 2; ++q)
        whi[q] = pack2(Wh_in[(2 * q) * GG + col], Wh_in[(2 * q + 1) * GG + col]);

    const float bo = b_out[col];
    const float bi = b_in[col];
    // branch-free activation: g<3 -> sigm(x); g==3 -> tanh(x)=2*sigm(2x)-1
    const float kk = (g == 3) ? 2.0f : 1.0f;
    const float aa = (g == 3) ? 2.0f : 1.0f;
    const float cc = (g == 3) ? -1.0f : 0.0f;

    const int   pn = j >> 3;
    const int   ps = j & 7;
    const float bl = b_lin[pn];

    // W_lin -> LDS fp16 (1024 chunks, 2 per thread)
#pragma unroll
    for (int r = 0; r < 2; ++r) {
        const int mm = r * 512 + j;
        const int c = mm >> 6, n = mm & 63;
        F4H u;
#pragma unroll
        for (int q = 0; q < 4; ++q)
            u.h[q] = pack2(W_lin[n * HH + 8 * c + 2 * q],
                           W_lin[n * HH + 8 * c + 2 * q + 1]);
        wlf[c * 66 + n] = u.f4;
    }

    if (j < HH) { hb[j] = (_Float16)0.f; xib[j] = (_Float16)0.f; hib[j] = (_Float16)0.f; }
    float c_reg = 0.f, cn_reg = 0.f;   // redundant in all 4 quad lanes
    float o_all = 0.f;                 // outer o, broadcast each step
    __syncthreads();

    const _Float16* xpr = xp + (size_t)b * SS * GG + col;
    float* orow = out + (size_t)b * SS * OO;
    const float4* hb4 = (const float4*)hb;   // 16 chunks
    const float4* xi4 = (const float4*)xib;  // 16 chunks
    const float4* hi4 = (const float4*)hib;  // 16 chunks

    _Float16 xpc = xpr[0];

#pragma unroll 1
    for (int t = 0; t < SS; ++t) {
        // ---- phase A: outer gate for col = XP + h@Wh_out + b ----
        float a0 = bo + (float)xpc, a1 = 0.f, a2 = 0.f, a3 = 0.f;
#pragma unroll
        for (int c = 0; c < 16; ++c) {
            F4H hu; hu.f4 = hb4[c];
            a0 = dot2(who[4 * c + 0], hu.h[0], a0);
            a1 = dot2(who[4 * c + 1], hu.h[1], a1);
            a2 = dot2(who[4 * c + 2], hu.h[2], a2);
            a3 = dot2(who[4 * c + 3], hu.h[3], a3);
        }
        // prefetch next step's XP (independent; lands during phase C)
        const _Float16 xpn = xpr[(size_t)((t + 1) & (SS - 1)) * GG];
        const float accA = (a0 + a1) + (a2 + a3);
        const float v = fmaf(aa, sigm(kk * accA), cc);   // i/f/o/g by lane
        // quad tail (DPP): x_in = i*g at lane0, h_in = f*c at lane1
        const float vg3 = qdpp<QP_XOR3>(v);   // lane0 <- g-value
        o_all = qdpp<QP_BC2>(v);              // everyone keeps outer o
        if (g == 0)      xib[m] = (_Float16)(v * vg3);
        else if (g == 1) hib[m] = (_Float16)(v * c_reg);  // c_reg redundant-valid
        __syncthreads();   // S1

        // ---- phase C: inner gate for col ----
        float c0 = bi, c1 = 0.f, c2 = 0.f, c3 = 0.f;
#pragma unroll
        for (int c = 0; c < 16; ++c) {
            F4H xu; xu.f4 = xi4[c];
            c0 = dot2(wxi[4 * c + 0], xu.h[0], c0);
            c1 = dot2(wxi[4 * c + 1], xu.h[1], c1);
            c2 = dot2(wxi[4 * c + 2], xu.h[2], c2);
            c3 = dot2(wxi[4 * c + 3], xu.h[3], c3);
        }
#pragma unroll
        for (int c = 0; c < 16; ++c) {
            F4H hu; hu.f4 = hi4[c];
            c0 = dot2(whi[4 * c + 0], hu.h[0], c0);
            c1 = dot2(whi[4 * c + 1], hu.h[1], c1);
            c2 = dot2(whi[4 * c + 2], hu.h[2], c2);
            c3 = dot2(whi[4 * c + 3], hu.h[3], c3);
        }
        const float accC = (c0 + c1) + (c2 + c3);
        const float u = fmaf(aa, sigm(kk * accC), cc);    // ii/fi/oi/gi by lane
        // quad tail (DPP, redundant update in all lanes; P/F/O independent):
        const float ug3 = qdpp<QP_XOR3>(u);
        const float p0  = u * ug3;                 // ii*gi valid at lanes 0,3
        const float P   = qdpp<QP_BC0>(p0);        // ii*gi everywhere
        const float F   = qdpp<QP_BC1>(u);         // fi everywhere
        const float O   = qdpp<QP_BC2>(u);         // oi everywhere
        const float cn_new = fmaf(F, cn_reg, P);
        cn_reg = cn_new;
        const float c_new = O * tanh_c(cn_new);
        c_reg = c_new;
        const float h_new = o_all * tanh_c(c_new);
        if (g == 2) hb[m] = (_Float16)h_new;
        xpc = xpn;
        __syncthreads();   // S2

        // ---- phase E: fused projection (overlaps next phase A in issue) ----
        float p = 0.f;
#pragma unroll
        for (int q = 0; q < 2; ++q) {
            const int c = 2 * ps + q;
            F4H hu; hu.f4 = hb4[c];
            F4H wu; wu.f4 = wlf[c * 66 + pn];
            p = dot2(wu.h[0], hu.h[0], p);
            p = dot2(wu.h[1], hu.h[1], p);
            p = dot2(wu.h[2], hu.h[2], p);
            p = dot2(wu.h[3], hu.h[3], p);
        }
        p += __shfl_down(p, 4, 8);
        p += __shfl_down(p, 2, 8);
        p += __shfl_down(p, 1, 8);
        if (ps == 0) orow[t * OO + pn] = p + bl;
    }
}

// ============================================================================
// FALLBACK: exact R1 kernel (measured 4364 us) for when ws is too small.
// ============================================================================
__global__ void
__attribute__((amdgpu_flat_work_group_size(512, 512)))
__attribute__((amdgpu_waves_per_eu(2, 2)))
nlstm_scan(
    const float* __restrict__ x,
    const float* __restrict__ Wx_out, const float* __restrict__ Wh_out,
    const float* __restrict__ b_out,
    const float* __restrict__ Wx_in, const float* __restrict__ Wh_in,
    const float* __restrict__ b_in,
    const float* __restrict__ W_lin, const float* __restrict__ b_lin,
    float* __restrict__ out)
{
    const int b = blockIdx.x;
    const int j = threadIdx.x;

    __shared__ __align__(16) float4 wxf[8 * 512];
    __shared__ __align__(16) float4 wlf[16 * 66];
    __shared__ float xt[2][II][TT + 1];
    __shared__ __align__(16) f16x2 xb[2][II / 2];
    __shared__ __align__(16) f16x2 hb[HH / 2];
    __shared__ __align__(16) f16x2 xib[HH / 2];
    __shared__ __align__(16) f16x2 hib[HH / 2];
    __shared__ float cb[HH];
    __shared__ float cnb[HH];
    __shared__ float actO[GG];
    __shared__ float actI[GG];

    f16x2 who[HH / 2], wxi[HH / 2], whi[HH / 2];
#pragma unroll
    for (int m = 0; m < HH / 2; ++m)
        who[m] = pack2(Wh_out[(2 * m) * GG + j], Wh_out[(2 * m + 1) * GG + j]);
#pragma unroll
    for (int m = 0; m < HH / 2; ++m)
        wxi[m] = pack2(Wx_in[(2 * m) * GG + j], Wx_in[(2 * m + 1) * GG + j]);
#pragma unroll
    for (int m = 0; m < HH / 2; ++m)
        whi[m] = pack2(Wh_in[(2 * m) * GG + j], Wh_in[(2 * m + 1) * GG + j]);

    const float bo = b_out[j];
    const float bi = b_in[j];
    const int   pn = j >> 3;
    const int   ps = j & 7;
    const float bl = b_lin[pn];

#pragma unroll
    for (int c = 0; c < 8; ++c) {
        F4H u;
#pragma unroll
        for (int q = 0; q < 4; ++q)
            u.h[q] = pack2(Wx_out[(8 * c + 2 * q) * GG + j],
                           Wx_out[(8 * c + 2 * q + 1) * GG + j]);
        wxf[c * 512 + j] = u.f4;
    }
#pragma unroll
    for (int r = 0; r < 2; ++r) {
        const int m = r * 512 + j;
        const int c = m >> 6, n = m & 63;
        F4H u;
#pragma unroll
        for (int q = 0; q < 4; ++q)
            u.h[q] = pack2(W_lin[n * HH + 8 * c + 2 * q],
                           W_lin[n * HH + 8 * c + 2 * q + 1]);
        wlf[c * 66 + n] = u.f4;
    }

    const float* xrow = x + (size_t)b * II * SS;
    float* orow = out + (size_t)b * SS * OO;

    {
        const int row = j >> 3, tc = j & 7;
        const float4 v = *(const float4*)(xrow + (size_t)row * SS + 4 * tc);
        float* dst = &xt[0][row][4 * tc];
        dst[0] = v.x; dst[1] = v.y; dst[2] = v.z; dst[3] = v.w;
    }
    if (j < HH / 2) hb[j] = pack2(0.f, 0.f);
    if (j < HH) { cb[j] = 0.f; cnb[j] = 0.f; }
    if (j >= 256 && j < 256 + 32) {
        const int m = j - 256;
        xb[0][m] = pack2(xrow[(2 * m) * SS], xrow[(2 * m + 1) * SS]);
    }
    __syncthreads();

    const float4* hb4 = (const float4*)hb;
    const float4* xi4 = (const float4*)xib;
    const float4* hi4 = (const float4*)hib;

#pragma unroll 1
    for (int t = 0; t < SS; ++t) {
        const float4* xcur = (const float4*)xb[t & 1];
        float a0 = bo, a1 = 0.f, a2 = 0.f, a3 = 0.f;
#pragma unroll
        for (int c = 0; c < 8; ++c) {
            F4H xu; xu.f4 = xcur[c];
            F4H wu; wu.f4 = wxf[c * 512 + j];
            a0 = dot2(wu.h[0], xu.h[0], a0);
            a1 = dot2(wu.h[1], xu.h[1], a1);
            a2 = dot2(wu.h[2], xu.h[2], a2);
            a3 = dot2(wu.h[3], xu.h[3], a3);
        }
#pragma unroll
        for (int c = 0; c < 16; ++c) {
            F4H hu; hu.f4 = hb4[c];
            a0 = dot2(who[4 * c + 0], hu.h[0], a0);
            a1 = dot2(who[4 * c + 1], hu.h[1], a1);
            a2 = dot2(who[4 * c + 2], hu.h[2], a2);
            a3 = dot2(who[4 * c + 3], hu.h[3], a3);
        }
        {
            const float acc = (a0 + a1) + (a2 + a3);
            actO[j] = (j < 384) ? sigm(acc) : tanh_f(acc);
        }
        __syncthreads();

        if (j < II) {
            xib[j] = pack2(actO[2 * j] * actO[384 + 2 * j],
                           actO[2 * j + 1] * actO[384 + 2 * j + 1]);
        } else if (j < II + HH / 2) {
            const int m = j - II;
            hib[m] = pack2(actO[HH + 2 * m] * cb[2 * m],
                           actO[HH + 2 * m + 1] * cb[2 * m + 1]);
        }
        __syncthreads();

        float c0 = bi, c1 = 0.f, c2 = 0.f, c3 = 0.f;
#pragma unroll
        for (int c = 0; c < 16; ++c) {
            F4H xu; xu.f4 = xi4[c];
            c0 = dot2(wxi[4 * c + 0], xu.h[0], c0);
            c1 = dot2(wxi[4 * c + 1], xu.h[1], c1);
            c2 = dot2(wxi[4 * c + 2], xu.h[2], c2);
            c3 = dot2(wxi[4 * c + 3], xu.h[3], c3);
        }
#pragma unroll
        for (int c = 0; c < 16; ++c) {
            F4H hu; hu.f4 = hi4[c];
            c0 = dot2(whi[4 * c + 0], hu.h[0], c0);
            c1 = dot2(whi[4 * c + 1], hu.h[1], c1);
            c2 = dot2(whi[4 * c + 2], hu.h[2], c2);
            c3 = dot2(whi[4 * c + 3], hu.h[3], c3);
        }
        {
            const float acc2 = (c0 + c1) + (c2 + c3);
            actI[j] = (j < 384) ? sigm(acc2) : tanh_f(acc2);
        }
        __syncthreads();

        const bool doTile = ((t & 31) == 30) && (t + 2 < SS);
        float4 xld; int Tn = 0;
        if (doTile) {
            Tn = (t + 2) >> 5;
            const int row = j >> 3, tc = j & 7;
            xld = *(const float4*)(xrow + (size_t)row * SS + TT * Tn + 4 * tc);
        }
        if (j < HH) {
            const float cn_new = actI[HH + j] * cnb[j] + actI[j] * actI[384 + j];
            const float c_new  = actI[2 * HH + j] * tanh_f(cn_new);
            const float h_new  = actO[2 * HH + j] * tanh_f(c_new);
            cnb[j] = cn_new;
            cb[j]  = c_new;
            ((_Float16*)hb)[j] = (_Float16)h_new;
        } else if (j < HH + 32) {
            const int m = j - HH;
            const int tn = t + 1;
            const int tbn = (tn >> 5) & 1, ttn = tn & 31;
            xb[tn & 1][m] = pack2(xt[tbn][2 * m][ttn],
                                  xt[tbn][2 * m + 1][ttn]);
        }
        if (doTile) {
            const int row = j >> 3, tc = j & 7;
            float* dst = &xt[Tn & 1][row][4 * tc];
            dst[0] = xld.x; dst[1] = xld.y; dst[2] = xld.z; dst[3] = xld.w;
        }
        __syncthreads();

        float p = 0.f;
#pragma unroll
        for (int q = 0; q < 2; ++q) {
            const int c = 2 * ps + q;
            F4H hu; hu.f4 = hb4[c];
            F4H wu; wu.f4 = wlf[c * 66 + pn];
            p = dot2(wu.h[0], hu.h[0], p);
            p = dot2(wu.h[1], hu.h[1], p);
            p = dot2(wu.h[2], hu.h[2], p);
            p = dot2(wu.h[3], hu.h[3], p);
        }
        p += __shfl_down(p, 4, 8);
        p += __shfl_down(p, 2, 8);
        p += __shfl_down(p, 1, 8);
        if (ps == 0) orow[t * OO + pn] = p + bl;
    }
}

extern "C" void kernel_launch(void* const* d_in, const int* in_sizes, int n_in,
                              void* d_out, int out_size, void* d_ws, size_t ws_size,
                              hipStream_t stream) {
    (void)in_sizes; (void)n_in; (void)out_size;
    const float* x      = (const float*)d_in[0];
    const float* Wx_out = (const float*)d_in[1];
    const float* Wh_out = (const float*)d_in[2];
    const float* b_out  = (const float*)d_in[3];
    const float* Wx_in  = (const float*)d_in[4];
    const float* Wh_in  = (const float*)d_in[5];
    const float* b_in   = (const float*)d_in[6];
    const float* W_lin  = (const float*)d_in[7];
    const float* b_lin  = (const float*)d_in[8];
    float* out = (float*)d_out;

    if (d_ws != nullptr && ws_size >= XPBYTES) {
        _Float16* xpw = (_Float16*)d_ws;
        xp_gemm<<<dim3(16, BB), dim3(512), 0, stream>>>(x, Wx_out, xpw);
        nlstm_scan_xp<<<dim3(BB), dim3(512), 0, stream>>>(
            xpw, Wh_out, b_out, Wx_in, Wh_in, b_in, W_lin, b_lin, out);
    } else {
        nlstm_scan<<<dim3(BB), dim3(512), 0, stream>>>(
            x, Wx_out, Wh_out, b_out, Wx_in, Wh_in, b_in, W_lin, b_lin, out);
    }
}